// Round 7
// baseline (256.785 us; speedup 1.0000x reference)
//
#include <hip/hip_runtime.h>
#include <hip/hip_bf16.h>
#include <stdint.h>

// QuantizedConv2d int8: x (32,128,56,56), w (256,128,3,3), pad 1, stride 1.
// Implicit GEMM on v_mfma_i32_32x32x32_i8. M=out-ch, N=pixels, K=9*128=1152.
// R7: wave tile 64ch x 64px (acc=64 AGPR -> 4-5 waves/SIMD resident), block
// 128ch x 2 rows, grid 1792. Tap-pair register double-buffer + sched_barrier
// fences (R6's proven pipeline) kept verbatim.

#define NB   32
#define CIN  128
#define HO   56
#define WO   56
#define KOUT 256
#define HP   58
#define ROWB (HP * CIN)          // 7424 bytes per padded row

typedef int v4i  __attribute__((ext_vector_type(4)));
typedef int v16i __attribute__((ext_vector_type(16)));

// ---------------- pack x: NCHW int32 -> padded NHWC int8, borders written ----
__global__ __launch_bounds__(256) void pack_x_kernel(const int* __restrict__ x,
                                                     int8_t* __restrict__ xp) {
  __shared__ int tile[WO][33];
  const int tid = threadIdx.x;
  const int r = blockIdx.x;          // padded row 0..57
  const int n = blockIdx.y;
  const int tx = tid & 63;
  const int ty = tid >> 6;
  const bool interior = (r >= 1) && (r <= HO);

  if (interior && tx < WO) {
    const int h = r - 1;
    #pragma unroll
    for (int c0 = 0; c0 < CIN; c0 += 16) {
      const int c = c0 + ty * 4;
      const int base = ((n * CIN + c) * HO + h) * WO + tx;
      const int v0 = x[base];
      const int v1 = x[base + HO * WO];
      const int v2 = x[base + 2 * HO * WO];
      const int v3 = x[base + 3 * HO * WO];
      tile[tx][c >> 2] = (v0 & 0xff) | ((v1 & 0xff) << 8) | ((v2 & 0xff) << 16) | (v3 << 24);
    }
  }
  __syncthreads();
  #pragma unroll
  for (int it = 0; it < 8; ++it) {
    const int i = it * 256 + tid;
    if (i < HP * 32) {
      const int w = i >> 5;
      const int c4 = i & 31;
      const int v = (interior && w >= 1 && w <= WO) ? tile[w - 1][c4] : 0;
      *reinterpret_cast<int*>(xp + ((size_t)(n * HP + r) * HP + w) * CIN + c4 * 4) = v;
    }
  }
}

// ---------------- pack w: OIHW int32 -> [kt(2)][tap(9)][n(128)][chunk(8)] 16B ----
__global__ __launch_bounds__(256) void pack_w_kernel(const int* __restrict__ wgt,
                                                     int8_t* __restrict__ wq) {
  const int wid = blockIdx.x * 256 + threadIdx.x;   // 0..73727 int32 words
  const int wi = wid & 3;
  const int ci = wid >> 2;                          // chunk 0..18431
  const int c   = ci & 7;
  const int nch = (ci >> 3) & 127;
  const int tt  = ci >> 10;                         // kt*9 + tap
  const int tap = tt % 9;
  const int kt  = tt / 9;
  const int k  = kt * 128 + nch;
  const int c0 = c * 16 + wi * 4;
  const int base = (k * CIN + c0) * 9 + tap;        // OIHW, 3x3=9 taps
  const int v0 = wgt[base];
  const int v1 = wgt[base + 9];
  const int v2 = wgt[base + 18];
  const int v3 = wgt[base + 27];
  reinterpret_cast<int*>(wq)[wid] =
      (v0 & 0xff) | ((v1 & 0xff) << 8) | ((v2 & 0xff) << 16) | (v3 << 24);
}

// ---------------- conv ----------------
// grid (28 rowpairs, 32 n, 2 kt) = 1792 blocks, 256 threads = 4 waves.
// Wave (wc: ch-half, wr: row): 64 ch x 64 px (one output row).
// acc[mt][nt] = 64 AGPR; weights register double-buffered per tap pair.
__global__ __launch_bounds__(256, 4) void conv_kernel(const int8_t* __restrict__ xp,
                                                      const int8_t* __restrict__ wq,
                                                      const int* __restrict__ bias,
                                                      const float* __restrict__ wscale,
                                                      int* __restrict__ out) {
  __shared__ __align__(16) int8_t lx[4 * HP * 8 * 16];   // 29,696 B: 4 padded rows
  __shared__ int   bsh[128];
  __shared__ float ssh[128];

  const int tid = threadIdx.x;
  const int h0 = blockIdx.x * 2;
  const int n_img = blockIdx.y;
  const int kt = blockIdx.z;

  const int lane = tid & 63;
  const int wid = tid >> 6;
  const int wc = wid & 1;            // 64-ch half
  const int wr = wid >> 1;           // output row within pair
  const int p0 = lane & 31;
  const int half = lane >> 5;

  const int8_t* xg = xp + ((size_t)(n_img * HP) + h0) * ROWB;
  const int8_t* wbase = wq + (size_t)kt * 147456;

  // ---- stage pixels: 4 padded rows, two-phase (all loads in flight) ----
  v4i tmp[8];
  #pragma unroll
  for (int it = 0; it < 8; ++it) {
    const int i = it * 256 + tid;                        // chunk slot < 1856
    if (i < 4 * HP * 8) {
      const int pf = i >> 3;
      const int cc = (i & 7) ^ (pf & 7);
      tmp[it] = *reinterpret_cast<const v4i*>(xg + pf * CIN + (cc << 4));
    }
  }
  #pragma unroll
  for (int it = 0; it < 8; ++it) {
    const int i = it * 256 + tid;
    if (i < 4 * HP * 8)
      *reinterpret_cast<v4i*>(lx + i * 16) = tmp[it];
  }
  if (tid < 128) {
    const int ch = kt * 128 + tid;
    bsh[tid] = bias[ch];
    ssh[tid] = (0.02f * wscale[ch]) / 0.05f;
  }
  __syncthreads();

  v16i acc[2][2];                    // [mt: 32-ch tile][nt: 32-px tile]
  #pragma unroll
  for (int mt = 0; mt < 2; ++mt)
    #pragma unroll
    for (int nt = 0; nt < 2; ++nt)
      #pragma unroll
      for (int e = 0; e < 16; ++e) acc[mt][nt][e] = 0;

  // weight fragment base: ch = wc*64 + mt*32 + p0, k-chunk = half + 2*ks
  const int8_t* ab = wbase + (wc * 64 + p0) * 128 + half * 16;

  v4i wfA[8], wfB[8];                // [ks*2 + mt]

#define PREFETCH(tapn, buf)                                                     \
  {                                                                             \
    const int8_t* tb = ab + (tapn) * 16384;                                     \
    _Pragma("unroll")                                                           \
    for (int ks = 0; ks < 4; ++ks)                                              \
      _Pragma("unroll")                                                         \
      for (int mt = 0; mt < 2; ++mt)                                            \
        buf[ks * 2 + mt] = *reinterpret_cast<const v4i*>(tb + mt * 4096 + ks * 32); \
  }

#define COMPUTE(tapn, buf)                                                      \
  {                                                                             \
    const int kh = (tapn) / 3, kw = (tapn) % 3;                                 \
    _Pragma("unroll")                                                           \
    for (int ks = 0; ks < 4; ++ks) {                                            \
      const int chb = (ks * 2 + half) << 4;                                     \
      _Pragma("unroll")                                                         \
      for (int nt = 0; nt < 2; ++nt) {                                          \
        const int pf = (wr + kh) * HP + kw + nt * 32 + p0;                      \
        const v4i b = *reinterpret_cast<const v4i*>(                            \
            lx + pf * CIN + (chb ^ ((pf & 7) << 4)));                           \
        acc[0][nt] = __builtin_amdgcn_mfma_i32_32x32x32_i8(                     \
            buf[ks * 2 + 0], b, acc[0][nt], 0, 0, 0);                           \
        acc[1][nt] = __builtin_amdgcn_mfma_i32_32x32x32_i8(                     \
            buf[ks * 2 + 1], b, acc[1][nt], 0, 0, 0);                           \
      }                                                                         \
    }                                                                           \
  }

  PREFETCH(0, wfA);
  #pragma unroll 1
  for (int t2 = 0; t2 < 4; ++t2) {
    const int tap = 2 * t2;
    PREFETCH(tap + 1, wfB);
    __builtin_amdgcn_sched_barrier(0);
    COMPUTE(tap, wfA);
    __builtin_amdgcn_sched_barrier(0);
    PREFETCH(tap + 2, wfA);
    __builtin_amdgcn_sched_barrier(0);
    COMPUTE(tap + 1, wfB);
    __builtin_amdgcn_sched_barrier(0);
  }
  COMPUTE(8, wfA);

  // ---- epilogue: D row = out-ch = mt*32 + (r&3)+8*(r>>2)+4*half, col = pixel ----
  const int h = h0 + wr;
  #pragma unroll
  for (int mt = 0; mt < 2; ++mt) {
    #pragma unroll
    for (int r = 0; r < 16; ++r) {
      const int cl = wc * 64 + mt * 32 + (r & 3) + 8 * (r >> 2) + 4 * half;
      const int bi = bsh[cl];
      const float sc = ssh[cl];
      int* ob = out + (((size_t)(n_img * KOUT + kt * 128 + cl)) * HO + h) * WO;
      #pragma unroll
      for (int nt = 0; nt < 2; ++nt) {
        const int w = nt * 32 + p0;
        if (w < WO) {
          float v = (float)(acc[mt][nt][r] + bi) * sc;
          v = rintf(v);
          v = fminf(fmaxf(v, -128.0f), 127.0f);
          ob[w] = (int)v;
        }
      }
    }
  }
#undef PREFETCH
#undef COMPUTE
}

extern "C" void kernel_launch(void* const* d_in, const int* in_sizes, int n_in,
                              void* d_out, int out_size, void* d_ws, size_t ws_size,
                              hipStream_t stream) {
  const int* x = (const int*)d_in[0];
  const int* wgt = (const int*)d_in[1];
  const int* bias = (const int*)d_in[2];
  const float* wscale = (const float*)d_in[3];
  int* out = (int*)d_out;

  int8_t* xp = (int8_t*)d_ws;                               // 13,780,992 B
  int8_t* wq = (int8_t*)d_ws + (size_t)NB * HP * ROWB;      // 294,912 B

  pack_x_kernel<<<dim3(HP, NB), 256, 0, stream>>>(x, xp);
  pack_w_kernel<<<288, 256, 0, stream>>>(wgt, wq);
  conv_kernel<<<dim3(28, 32, 2), 256, 0, stream>>>(xp, wq, bias, wscale, out);
}

// Round 8
// 206.000 us; speedup vs baseline: 1.2465x; 1.2465x over previous
//
#include <hip/hip_runtime.h>
#include <hip/hip_bf16.h>
#include <stdint.h>

// QuantizedConv2d int8: x (32,128,56,56), w (256,128,3,3), pad 1, stride 1.
// Implicit GEMM on v_mfma_i32_32x32x32_i8. M=out-ch, N=pixels, K=9*128=1152.
// R8: R7's 64ch x 64px wave tile (acc=64 AGPR) + launch_bounds(256,3) so the
// tap-pair register double-buffer does NOT spill (R7's 256,4 spilled: WRITE
// 275 MB). x staged via global_load_lds width=16 (no tmp VGPRs).

#define NB   32
#define CIN  128
#define HO   56
#define WO   56
#define KOUT 256
#define HP   58
#define ROWB (HP * CIN)          // 7424 bytes per padded row

typedef int v4i  __attribute__((ext_vector_type(4)));
typedef int v16i __attribute__((ext_vector_type(16)));

static __device__ __forceinline__ void gload_lds16(const int8_t* g, int8_t* l) {
  __builtin_amdgcn_global_load_lds(
      (const __attribute__((address_space(1))) void*)g,
      (__attribute__((address_space(3))) void*)l, 16, 0, 0);
}

// ---------------- pack x: NCHW int32 -> padded NHWC int8, borders written ----
__global__ __launch_bounds__(256) void pack_x_kernel(const int* __restrict__ x,
                                                     int8_t* __restrict__ xp) {
  __shared__ int tile[WO][33];
  const int tid = threadIdx.x;
  const int r = blockIdx.x;          // padded row 0..57
  const int n = blockIdx.y;
  const int tx = tid & 63;
  const int ty = tid >> 6;
  const bool interior = (r >= 1) && (r <= HO);

  if (interior && tx < WO) {
    const int h = r - 1;
    #pragma unroll
    for (int c0 = 0; c0 < CIN; c0 += 16) {
      const int c = c0 + ty * 4;
      const int base = ((n * CIN + c) * HO + h) * WO + tx;
      const int v0 = x[base];
      const int v1 = x[base + HO * WO];
      const int v2 = x[base + 2 * HO * WO];
      const int v3 = x[base + 3 * HO * WO];
      tile[tx][c >> 2] = (v0 & 0xff) | ((v1 & 0xff) << 8) | ((v2 & 0xff) << 16) | (v3 << 24);
    }
  }
  __syncthreads();
  #pragma unroll
  for (int it = 0; it < 8; ++it) {
    const int i = it * 256 + tid;
    if (i < HP * 32) {
      const int w = i >> 5;
      const int c4 = i & 31;
      const int v = (interior && w >= 1 && w <= WO) ? tile[w - 1][c4] : 0;
      *reinterpret_cast<int*>(xp + ((size_t)(n * HP + r) * HP + w) * CIN + c4 * 4) = v;
    }
  }
}

// ---------------- pack w: OIHW int32 -> [kt(2)][tap(9)][n(128)][chunk(8)] 16B ----
__global__ __launch_bounds__(256) void pack_w_kernel(const int* __restrict__ wgt,
                                                     int8_t* __restrict__ wq) {
  const int wid = blockIdx.x * 256 + threadIdx.x;   // 0..73727 int32 words
  const int wi = wid & 3;
  const int ci = wid >> 2;                          // chunk 0..18431
  const int c   = ci & 7;
  const int nch = (ci >> 3) & 127;
  const int tt  = ci >> 10;                         // kt*9 + tap
  const int tap = tt % 9;
  const int kt  = tt / 9;
  const int k  = kt * 128 + nch;
  const int c0 = c * 16 + wi * 4;
  const int base = (k * CIN + c0) * 9 + tap;        // OIHW, 3x3=9 taps
  const int v0 = wgt[base];
  const int v1 = wgt[base + 9];
  const int v2 = wgt[base + 18];
  const int v3 = wgt[base + 27];
  reinterpret_cast<int*>(wq)[wid] =
      (v0 & 0xff) | ((v1 & 0xff) << 8) | ((v2 & 0xff) << 16) | (v3 << 24);
}

// ---------------- conv ----------------
// grid (28 rowpairs, 32 n, 2 kt) = 1792 blocks, 256 threads = 4 waves.
// Wave (wc: ch-half, wr: row): 64 ch x 64 px (one output row).
// acc[mt][nt] = 64 AGPR; weights register double-buffered per tap pair.
__global__ __launch_bounds__(256, 3) void conv_kernel(const int8_t* __restrict__ xp,
                                                      const int8_t* __restrict__ wq,
                                                      const int* __restrict__ bias,
                                                      const float* __restrict__ wscale,
                                                      int* __restrict__ out) {
  __shared__ __align__(16) int8_t lx[4 * HP * 8 * 16];   // 29,696 B: 4 padded rows
  __shared__ int   bsh[128];
  __shared__ float ssh[128];

  const int tid = threadIdx.x;
  const int h0 = blockIdx.x * 2;
  const int n_img = blockIdx.y;
  const int kt = blockIdx.z;

  const int lane = tid & 63;
  const int wid = tid >> 6;
  const int wc = wid & 1;            // 64-ch half
  const int wr = wid >> 1;           // output row within pair
  const int p0 = lane & 31;
  const int half = lane >> 5;

  const int8_t* xg = xp + ((size_t)(n_img * HP) + h0) * ROWB;
  const int8_t* wbase = wq + (size_t)kt * 147456;

  // ---- stage pixels via global_load_lds (16B/lane, linear LDS slots) ----
  // slot i holds chunk (i&7)^((i>>3)&7) of flat pixel i>>3 (XOR swizzle in
  // the *global* source address; LDS layout is linear -> wave-uniform base).
  #pragma unroll
  for (int it = 0; it < 8; ++it) {
    const int i = it * 256 + tid;                        // slot < 1856
    if (i < 4 * HP * 8) {
      const int pf = i >> 3;
      const int cc = (i & 7) ^ (pf & 7);
      gload_lds16(xg + pf * CIN + (cc << 4),
                  lx + (it * 256 + (wid << 6)) * 16);    // wave-uniform base
    }
  }
  if (tid < 128) {
    const int ch = kt * 128 + tid;
    bsh[tid] = bias[ch];
    ssh[tid] = (0.02f * wscale[ch]) / 0.05f;
  }
  __syncthreads();

  v16i acc[2][2];                    // [mt: 32-ch tile][nt: 32-px tile]
  #pragma unroll
  for (int mt = 0; mt < 2; ++mt)
    #pragma unroll
    for (int nt = 0; nt < 2; ++nt)
      #pragma unroll
      for (int e = 0; e < 16; ++e) acc[mt][nt][e] = 0;

  // weight fragment base: ch = wc*64 + mt*32 + p0, k-chunk = half + 2*ks
  const int8_t* ab = wbase + (wc * 64 + p0) * 128 + half * 16;

  v4i wfA[8], wfB[8];                // [ks*2 + mt]

#define PREFETCH(tapn, buf)                                                     \
  {                                                                             \
    const int8_t* tb = ab + (tapn) * 16384;                                     \
    _Pragma("unroll")                                                           \
    for (int ks = 0; ks < 4; ++ks)                                              \
      _Pragma("unroll")                                                         \
      for (int mt = 0; mt < 2; ++mt)                                            \
        buf[ks * 2 + mt] = *reinterpret_cast<const v4i*>(tb + mt * 4096 + ks * 32); \
  }

#define COMPUTE(tapn, buf)                                                      \
  {                                                                             \
    const int kh = (tapn) / 3, kw = (tapn) % 3;                                 \
    _Pragma("unroll")                                                           \
    for (int ks = 0; ks < 4; ++ks) {                                            \
      const int chb = (ks * 2 + half) << 4;                                     \
      _Pragma("unroll")                                                         \
      for (int nt = 0; nt < 2; ++nt) {                                          \
        const int pf = (wr + kh) * HP + kw + nt * 32 + p0;                      \
        const v4i b = *reinterpret_cast<const v4i*>(                            \
            lx + pf * CIN + (chb ^ ((pf & 7) << 4)));                           \
        acc[0][nt] = __builtin_amdgcn_mfma_i32_32x32x32_i8(                     \
            buf[ks * 2 + 0], b, acc[0][nt], 0, 0, 0);                           \
        acc[1][nt] = __builtin_amdgcn_mfma_i32_32x32x32_i8(                     \
            buf[ks * 2 + 1], b, acc[1][nt], 0, 0, 0);                           \
      }                                                                         \
    }                                                                           \
  }

  PREFETCH(0, wfA);
  #pragma unroll 1
  for (int t2 = 0; t2 < 4; ++t2) {
    const int tap = 2 * t2;
    PREFETCH(tap + 1, wfB);
    __builtin_amdgcn_sched_barrier(0);
    COMPUTE(tap, wfA);
    __builtin_amdgcn_sched_barrier(0);
    PREFETCH(tap + 2, wfA);
    __builtin_amdgcn_sched_barrier(0);
    COMPUTE(tap + 1, wfB);
    __builtin_amdgcn_sched_barrier(0);
  }
  COMPUTE(8, wfA);

  // ---- epilogue: D row = out-ch = mt*32 + (r&3)+8*(r>>2)+4*half, col = pixel ----
  const int h = h0 + wr;
  #pragma unroll
  for (int mt = 0; mt < 2; ++mt) {
    #pragma unroll
    for (int r = 0; r < 16; ++r) {
      const int cl = wc * 64 + mt * 32 + (r & 3) + 8 * (r >> 2) + 4 * half;
      const int bi = bsh[cl];
      const float sc = ssh[cl];
      int* ob = out + (((size_t)(n_img * KOUT + kt * 128 + cl)) * HO + h) * WO;
      #pragma unroll
      for (int nt = 0; nt < 2; ++nt) {
        const int w = nt * 32 + p0;
        if (w < WO) {
          float v = (float)(acc[mt][nt][r] + bi) * sc;
          v = rintf(v);
          v = fminf(fmaxf(v, -128.0f), 127.0f);
          ob[w] = (int)v;
        }
      }
    }
  }
#undef PREFETCH
#undef COMPUTE
}

extern "C" void kernel_launch(void* const* d_in, const int* in_sizes, int n_in,
                              void* d_out, int out_size, void* d_ws, size_t ws_size,
                              hipStream_t stream) {
  const int* x = (const int*)d_in[0];
  const int* wgt = (const int*)d_in[1];
  const int* bias = (const int*)d_in[2];
  const float* wscale = (const float*)d_in[3];
  int* out = (int*)d_out;

  int8_t* xp = (int8_t*)d_ws;                               // 13,780,992 B
  int8_t* wq = (int8_t*)d_ws + (size_t)NB * HP * ROWB;      // 294,912 B

  pack_x_kernel<<<dim3(HP, NB), 256, 0, stream>>>(x, xp);
  pack_w_kernel<<<288, 256, 0, stream>>>(wgt, wq);
  conv_kernel<<<dim3(28, 32, 2), 256, 0, stream>>>(xp, wq, bias, wscale, out);
}

// Round 9
// 185.227 us; speedup vs baseline: 1.3863x; 1.1121x over previous
//
#include <hip/hip_runtime.h>
#include <hip/hip_bf16.h>
#include <stdint.h>

// QuantizedConv2d int8: x (32,128,56,56), w (256,128,3,3), pad 1, stride 1.
// Implicit GEMM on v_mfma_i32_32x32x32_i8. M=out-ch, N=pixels, K=9*128=1152.
// R9: ALL weights for the block's 64-ch slice (9 taps, 72 KB) + 10 x-rows
// (74 KB) resident in LDS; K-loop has ZERO global loads and ZERO barriers.
// 512 threads = 8 waves (one output row each), 2 waves/SIMD. Weights stored
// chunk-major [tap][cc][ch] -> stride-1 conflict-free A reads.

#define NB   32
#define CIN  128
#define HO   56
#define WO   56
#define KOUT 256
#define HP   58
#define ROWB (HP * CIN)          // 7424 bytes per padded row

typedef int v4i  __attribute__((ext_vector_type(4)));
typedef int v16i __attribute__((ext_vector_type(16)));

static __device__ __forceinline__ void gload_lds16(const int8_t* g, int8_t* l) {
  __builtin_amdgcn_global_load_lds(
      (const __attribute__((address_space(1))) void*)g,
      (__attribute__((address_space(3))) void*)l, 16, 0, 0);
}

// ---------------- pack x: NCHW int32 -> padded NHWC int8 (int4 reads) --------
__global__ __launch_bounds__(256) void pack_x_kernel(const int* __restrict__ x,
                                                     int8_t* __restrict__ xp) {
  __shared__ int t32[128][57];       // 29,184 B, stride 57 to break conflicts
  const int tid = threadIdx.x;
  const int r = blockIdx.x;          // padded row 0..57
  const int n = blockIdx.y;
  const bool interior = (r >= 1) && (r <= HO);

  if (interior) {
    const int h = r - 1;
    const int* xrow = x + ((size_t)(n * CIN) * HO + h) * WO;  // c stride = 3136 ints
    #pragma unroll
    for (int it = 0; it < 7; ++it) {
      const int j = it * 256 + tid;  // < 1792 = 128 c x 14 w-quads
      const int c = j / 14;
      const int w4 = j - c * 14;
      const int4 v = *reinterpret_cast<const int4*>(xrow + c * 3136 + w4 * 4);
      t32[c][w4 * 4 + 0] = v.x;
      t32[c][w4 * 4 + 1] = v.y;
      t32[c][w4 * 4 + 2] = v.z;
      t32[c][w4 * 4 + 3] = v.w;
    }
  }
  __syncthreads();
  #pragma unroll
  for (int it = 0; it < 8; ++it) {
    const int i = it * 256 + tid;
    if (i < HP * 32) {
      const int w = i >> 5;          // padded col 0..57
      const int c4 = i & 31;
      int vv = 0;
      if (interior && w >= 1 && w <= WO) {
        const int b0 = t32[c4 * 4 + 0][w - 1] & 0xff;
        const int b1 = t32[c4 * 4 + 1][w - 1] & 0xff;
        const int b2 = t32[c4 * 4 + 2][w - 1] & 0xff;
        const int b3 = t32[c4 * 4 + 3][w - 1];
        vv = b0 | (b1 << 8) | (b2 << 16) | (b3 << 24);
      }
      *reinterpret_cast<int*>(xp + ((size_t)(n * HP + r) * HP + w) * CIN + c4 * 4) = vv;
    }
  }
}

// ------ pack w: OIHW int32 -> [kt(4)][tap(9)][cc(8)][ch(64)] 16B chunks ------
__global__ __launch_bounds__(256) void pack_w_kernel(const int* __restrict__ wgt,
                                                     int8_t* __restrict__ wq) {
  const int wid = blockIdx.x * 256 + threadIdx.x;   // 0..73727 int32 words
  const int wi = wid & 3;
  const int ci = wid >> 2;                          // chunk 0..18431
  const int kt = ci / 4608;                         // 4608 = 9*8*64
  const int r  = ci - kt * 4608;
  const int tap = r >> 9;                           // 512 = 8*64
  const int r2  = r & 511;
  const int cc  = r2 >> 6;
  const int ch  = r2 & 63;
  const int k_global = kt * 64 + ch;
  const int cin0 = cc * 16 + wi * 4;
  const int base = (k_global * CIN + cin0) * 9 + tap;  // OIHW, 3x3=9 taps
  const int v0 = wgt[base];
  const int v1 = wgt[base + 9];
  const int v2 = wgt[base + 18];
  const int v3 = wgt[base + 27];
  reinterpret_cast<int*>(wq)[wid] =
      (v0 & 0xff) | ((v1 & 0xff) << 8) | ((v2 & 0xff) << 16) | (v3 << 24);
}

// ---------------- conv: all-LDS K-loop ----------------
// grid (4 kt, 7 rowgroups, 32 n) = 896 blocks, 512 threads = 8 waves.
// Block: 64 out-ch x 8 output rows. Wave wr: row h0+wr, 64 ch x 64 px.
// acc[mt][nt] = 64 AGPR. K-loop: 4 LDS b128 reads per 4 MFMAs, no barriers.
__global__ __launch_bounds__(512, 2) void conv_kernel(const int8_t* __restrict__ xp,
                                                      const int8_t* __restrict__ wq,
                                                      const int* __restrict__ bias,
                                                      const float* __restrict__ wscale,
                                                      int* __restrict__ out) {
  __shared__ __align__(16) int8_t lw[9 * 8 * 64 * 16];   // 73,728 B: all taps, 64 ch
  __shared__ __align__(16) int8_t lx[10 * HP * 8 * 16];  // 74,240 B: 10 padded rows
  __shared__ int   bsh[64];
  __shared__ float ssh[64];

  const int tid = threadIdx.x;
  const int kt = blockIdx.x;           // 64-ch slice
  const int h0 = blockIdx.y * 8;
  const int n_img = blockIdx.z;

  const int lane = tid & 63;
  const int wr = tid >> 6;             // wave = output row 0..7
  const int p0 = lane & 31;
  const int half = lane >> 5;

  const int8_t* xg = xp + ((size_t)(n_img * HP) + h0) * ROWB;
  const int8_t* wqt = wq + (size_t)kt * 73728;

  // ---- stage weights: 4608 chunks, linear (layout pre-swizzled by pack_w) ----
  #pragma unroll
  for (int it = 0; it < 9; ++it) {
    const int j = it * 512 + tid;
    gload_lds16(wqt + j * 16, lw + j * 16);
  }
  // ---- stage pixels: 10 padded rows = 4640 chunks, XOR swizzle in source ----
  #pragma unroll
  for (int it = 0; it < 10; ++it) {
    const int i = it * 512 + tid;
    if (i < 10 * HP * 8) {
      const int pf = i >> 3;
      const int cc = (i & 7) ^ (pf & 7);
      gload_lds16(xg + pf * CIN + (cc << 4), lx + i * 16);
    }
  }
  if (tid < 64) {
    const int ch = kt * 64 + tid;
    bsh[tid] = bias[ch];
    ssh[tid] = (0.02f * wscale[ch]) / 0.05f;   // IN_SCALE * ws / OUT_SCALE
  }
  __syncthreads();

  v16i acc[2][2];                      // [mt: 32-ch tile][nt: 32-px tile]
  #pragma unroll
  for (int mt = 0; mt < 2; ++mt)
    #pragma unroll
    for (int nt = 0; nt < 2; ++nt)
      #pragma unroll
      for (int e = 0; e < 16; ++e) acc[mt][nt][e] = 0;

  #pragma unroll
  for (int tap = 0; tap < 9; ++tap) {
    const int kh = tap / 3, kw = tap % 3;
    const int8_t* lwt = lw + tap * 8192;         // [cc(8)][ch(64)] chunk-major
    const int pfb = (wr + kh) * HP + kw;
    #pragma unroll
    for (int ks = 0; ks < 4; ++ks) {
      const int cch = 2 * ks + half;             // k-chunk for this lane
      const v4i a0 = *reinterpret_cast<const v4i*>(lwt + cch * 1024 + p0 * 16);
      const v4i a1 = *reinterpret_cast<const v4i*>(lwt + cch * 1024 + (32 + p0) * 16);
      #pragma unroll
      for (int nt = 0; nt < 2; ++nt) {
        const int pf = pfb + nt * 32 + p0;
        const v4i b = *reinterpret_cast<const v4i*>(
            lx + pf * CIN + ((cch ^ (pf & 7)) << 4));
        acc[0][nt] = __builtin_amdgcn_mfma_i32_32x32x32_i8(a0, b, acc[0][nt], 0, 0, 0);
        acc[1][nt] = __builtin_amdgcn_mfma_i32_32x32x32_i8(a1, b, acc[1][nt], 0, 0, 0);
      }
    }
  }

  // ---- epilogue: D row = ch = mt*32 + (r&3)+8*(r>>2)+4*half, col = pixel ----
  const int h = h0 + wr;
  #pragma unroll
  for (int mt = 0; mt < 2; ++mt) {
    #pragma unroll
    for (int r = 0; r < 16; ++r) {
      const int cl = mt * 32 + (r & 3) + 8 * (r >> 2) + 4 * half;
      const int bi = bsh[cl];
      const float sc = ssh[cl];
      int* ob = out + (((size_t)(n_img * KOUT + kt * 64 + cl)) * HO + h) * WO;
      #pragma unroll
      for (int nt = 0; nt < 2; ++nt) {
        const int w = nt * 32 + p0;
        if (w < WO) {
          float v = (float)(acc[mt][nt][r] + bi) * sc;
          v = rintf(v);                          // round-half-even == jnp.round
          v = fminf(fmaxf(v, -128.0f), 127.0f);
          ob[w] = (int)v;
        }
      }
    }
  }
}

extern "C" void kernel_launch(void* const* d_in, const int* in_sizes, int n_in,
                              void* d_out, int out_size, void* d_ws, size_t ws_size,
                              hipStream_t stream) {
  const int* x = (const int*)d_in[0];
  const int* wgt = (const int*)d_in[1];
  const int* bias = (const int*)d_in[2];
  const float* wscale = (const float*)d_in[3];
  int* out = (int*)d_out;

  int8_t* xp = (int8_t*)d_ws;                               // 13,780,992 B
  int8_t* wq = (int8_t*)d_ws + (size_t)NB * HP * ROWB;      // 294,912 B

  pack_x_kernel<<<dim3(HP, NB), 256, 0, stream>>>(x, xp);
  pack_w_kernel<<<288, 256, 0, stream>>>(wgt, wq);
  conv_kernel<<<dim3(4, 7, 32), 512, 0, stream>>>(xp, wq, bias, wscale, out);
}